// Round 2
// baseline (2177.311 us; speedup 1.0000x reference)
//
#include <hip/hip_runtime.h>

#define DEPTHL 4
#define NHEADS 8
#define DIMC 512
#define HIDDENC 1024
#define NTOK 17
#define NROWS (2048*NTOK)   // 34816

typedef __attribute__((ext_vector_type(8))) short s8v;
typedef __attribute__((ext_vector_type(4))) float f4v;
typedef __attribute__((ext_vector_type(4))) short s4v;

static __device__ __forceinline__ float bf2f(short s) {
  unsigned u = ((unsigned)(unsigned short)s) << 16;
  return __builtin_bit_cast(float, u);
}
static __device__ __forceinline__ short f2bf(float f) {
  unsigned u = __builtin_bit_cast(unsigned, f);
  u += 0x7fffu + ((u >> 16) & 1u);
  return (short)(u >> 16);
}

static __device__ __forceinline__ void load_lds16(const void* g, void* l) {
  __builtin_amdgcn_global_load_lds(
      (const __attribute__((address_space(1))) unsigned int*)g,
      (__attribute__((address_space(3))) unsigned int*)l, 16, 0, 0);
}

#define BARX() asm volatile("s_barrier" ::: "memory")
#define VMC(n) asm volatile("s_waitcnt vmcnt(" #n ")" ::: "memory")

// ---------------- weight fp32 -> bf16 convert ----------------
__global__ __launch_bounds__(256) void f2bf_kernel(const float* __restrict__ in,
                                                   short* __restrict__ out, int n4) {
  int i = blockIdx.x * 256 + threadIdx.x;
  if (i < n4) {
    float4 v = ((const float4*)in)[i];
    s4v o;
    o[0] = f2bf(v.x); o[1] = f2bf(v.y); o[2] = f2bf(v.z); o[3] = f2bf(v.w);
    ((s4v*)out)[i] = o;
  }
}

// ---------------- LayerNorm -> bf16 ----------------
__global__ __launch_bounds__(256) void ln_kernel(const float* __restrict__ x,
    const float* __restrict__ g, const float* __restrict__ b,
    short* __restrict__ h) {
  int row = blockIdx.x * 4 + (threadIdx.x >> 6);
  int lane = threadIdx.x & 63;
  const float* xr = x + (size_t)row * DIMC + lane * 8;
  float4 v0 = *(const float4*)xr;
  float4 v1 = *(const float4*)(xr + 4);
  float s = v0.x + v0.y + v0.z + v0.w + v1.x + v1.y + v1.z + v1.w;
  #pragma unroll
  for (int o = 32; o > 0; o >>= 1) s += __shfl_xor(s, o, 64);
  float mean = s * (1.0f / 512.0f);
  float d0 = v0.x-mean, d1 = v0.y-mean, d2 = v0.z-mean, d3 = v0.w-mean;
  float d4 = v1.x-mean, d5 = v1.y-mean, d6 = v1.z-mean, d7 = v1.w-mean;
  float vs = d0*d0+d1*d1+d2*d2+d3*d3+d4*d4+d5*d5+d6*d6+d7*d7;
  #pragma unroll
  for (int o = 32; o > 0; o >>= 1) vs += __shfl_xor(vs, o, 64);
  float rstd = rsqrtf(vs * (1.0f / 512.0f) + 1e-5f);
  const float* gp = g + lane * 8;
  const float* bp = b + lane * 8;
  float4 g0 = *(const float4*)gp, g1 = *(const float4*)(gp + 4);
  float4 b0 = *(const float4*)bp, b1 = *(const float4*)(bp + 4);
  s8v o;
  o[0] = f2bf(d0 * rstd * g0.x + b0.x);
  o[1] = f2bf(d1 * rstd * g0.y + b0.y);
  o[2] = f2bf(d2 * rstd * g0.z + b0.z);
  o[3] = f2bf(d3 * rstd * g0.w + b0.w);
  o[4] = f2bf(d4 * rstd * g1.x + b1.x);
  o[5] = f2bf(d5 * rstd * g1.y + b1.y);
  o[6] = f2bf(d6 * rstd * g1.z + b1.z);
  o[7] = f2bf(d7 * rstd * g1.w + b1.w);
  *(s8v*)(h + (size_t)row * DIMC + lane * 8) = o;
}

// ---------------- 8-phase 256^2 GEMM: out[m,n] = sum_k A[m,k]*W[n,k] ----------------
enum { EPI_BF16 = 0, EPI_RES_F32 = 1, EPI_GELU_BF16 = 2 };

template<int K, int EPI>
__global__ __launch_bounds__(512, 2) void gemm8p(
    const short* __restrict__ A, const short* __restrict__ Bm,
    const float* __restrict__ bias, const float* __restrict__ res,
    void* __restrict__ outp, int N, int nbx) {
  constexpr int NT = K / 64;
  __shared__ __align__(16) short SA[2][16384];  // [buf][256*64] swizzled
  __shared__ __align__(16) short SB[2][16384];
  const int tid = threadIdx.x;
  const int wave = tid >> 6, lane = tid & 63;
  const int l15 = lane & 15, l4 = lane >> 4;
  // T1 XCD swizzle (grid always divisible by 8 here)
  const int nwg = gridDim.x;
  const int bid = blockIdx.x;
  const int swz = (bid & 7) * (nwg >> 3) + (bid >> 3);
  const int bx = swz % nbx, by = swz / nbx;
  const int m0 = by * 256, n0 = bx * 256;
  const int wr = wave >> 2, wcn = wave & 3;

  f4v acc[8][4] = {};
  s8v a[4][2], b[2][2];

  // stage one 64-row quarter (1 load/thread): linear LDS dest, inverse-swizzled src
  auto stage = [&](const short* __restrict__ mat, int row0, int k0, short* ldsu) {
    const int r = tid >> 3, c = tid & 7;
    const short* src = mat + (size_t)(row0 + r) * K + k0 + ((c ^ (r & 7)) << 3);
    load_lds16(src, ldsu + ((tid & ~63) << 3));
  };
  // swizzled ds_read of one MFMA A/B fragment
  auto rdA = [&](int buf, int R, int ks) -> s8v {
    return *(const s8v*)&SA[buf][(R << 6) + ((ks ^ (R & 7)) << 3)];
  };
  auto rdB = [&](int buf, int R, int ks) -> s8v {
    return *(const s8v*)&SB[buf][(R << 6) + ((ks ^ (R & 7)) << 3)];
  };

  // ---- prologue: tile0 (A+B), tile1 (A); B(1) staged at p1(0) ----
  #pragma unroll
  for (int q = 0; q < 4; ++q) stage(A, m0 + q * 64, 0, &SA[0][q * 4096]);
  #pragma unroll
  for (int q = 0; q < 4; ++q) stage(Bm, n0 + q * 64, 0, &SB[0][q * 4096]);
  #pragma unroll
  for (int q = 0; q < 4; ++q) stage(A, m0 + q * 64, 64, &SA[1][q * 4096]);
  VMC(4);
  BARX();

  #pragma unroll 2
  for (int t = 0; t < NT; ++t) {
    const int buf = t & 1, nbuf = buf ^ 1;
    // ---- p1: quadrant (0,0); stage B quarters of t+1 ----
    #pragma unroll
    for (int i2 = 0; i2 < 4; ++i2)
      #pragma unroll
      for (int kk = 0; kk < 2; ++kk)
        a[i2][kk] = rdA(buf, wr * 128 + i2 * 16 + l15, kk * 4 + l4);
    #pragma unroll
    for (int j2 = 0; j2 < 2; ++j2)
      #pragma unroll
      for (int kk = 0; kk < 2; ++kk)
        b[j2][kk] = rdB(buf, wcn * 64 + j2 * 16 + l15, kk * 4 + l4);
    if (t + 1 < NT) {
      #pragma unroll
      for (int q = 0; q < 4; ++q)
        stage(Bm, n0 + q * 64, (t + 1) * 64, &SB[nbuf][q * 4096]);
    }
    BARX();
    __builtin_amdgcn_sched_barrier(0);
    __builtin_amdgcn_s_setprio(1);
    #pragma unroll
    for (int i2 = 0; i2 < 4; ++i2)
      #pragma unroll
      for (int j2 = 0; j2 < 2; ++j2)
        #pragma unroll
        for (int kk = 0; kk < 2; ++kk)
          acc[i2][j2] = __builtin_amdgcn_mfma_f32_16x16x32_bf16(a[i2][kk], b[j2][kk], acc[i2][j2], 0, 0, 0);
    __builtin_amdgcn_s_setprio(0);
    BARX();

    // ---- p2: quadrant (0,1); stage A q0,q2 of t+2 ----
    #pragma unroll
    for (int j2 = 0; j2 < 2; ++j2)
      #pragma unroll
      for (int kk = 0; kk < 2; ++kk)
        b[j2][kk] = rdB(buf, wcn * 64 + 32 + j2 * 16 + l15, kk * 4 + l4);
    if (t + 2 < NT) {
      stage(A, m0 + 0,   (t + 2) * 64, &SA[buf][0]);
      stage(A, m0 + 128, (t + 2) * 64, &SA[buf][2 * 4096]);
    }
    BARX();
    __builtin_amdgcn_sched_barrier(0);
    __builtin_amdgcn_s_setprio(1);
    #pragma unroll
    for (int i2 = 0; i2 < 4; ++i2)
      #pragma unroll
      for (int j2 = 0; j2 < 2; ++j2)
        #pragma unroll
        for (int kk = 0; kk < 2; ++kk)
          acc[i2][2 + j2] = __builtin_amdgcn_mfma_f32_16x16x32_bf16(a[i2][kk], b[j2][kk], acc[i2][2 + j2], 0, 0, 0);
    __builtin_amdgcn_s_setprio(0);
    BARX();

    // ---- p3: quadrant (1,1) ----
    #pragma unroll
    for (int i2 = 0; i2 < 4; ++i2)
      #pragma unroll
      for (int kk = 0; kk < 2; ++kk)
        a[i2][kk] = rdA(buf, wr * 128 + 64 + i2 * 16 + l15, kk * 4 + l4);
    BARX();
    __builtin_amdgcn_sched_barrier(0);
    __builtin_amdgcn_s_setprio(1);
    #pragma unroll
    for (int i2 = 0; i2 < 4; ++i2)
      #pragma unroll
      for (int j2 = 0; j2 < 2; ++j2)
        #pragma unroll
        for (int kk = 0; kk < 2; ++kk)
          acc[4 + i2][2 + j2] = __builtin_amdgcn_mfma_f32_16x16x32_bf16(a[i2][kk], b[j2][kk], acc[4 + i2][2 + j2], 0, 0, 0);
    __builtin_amdgcn_s_setprio(0);
    BARX();

    // ---- p4: quadrant (1,0); stage A q1,q3 of t+2; counted vmcnt ----
    #pragma unroll
    for (int j2 = 0; j2 < 2; ++j2)
      #pragma unroll
      for (int kk = 0; kk < 2; ++kk)
        b[j2][kk] = rdB(buf, wcn * 64 + j2 * 16 + l15, kk * 4 + l4);
    if (t + 2 < NT) {
      stage(A, m0 + 64,  (t + 2) * 64, &SA[buf][1 * 4096]);
      stage(A, m0 + 192, (t + 2) * 64, &SA[buf][3 * 4096]);
      VMC(8);
    } else {
      VMC(0);
    }
    BARX();
    __builtin_amdgcn_sched_barrier(0);
    __builtin_amdgcn_s_setprio(1);
    #pragma unroll
    for (int i2 = 0; i2 < 4; ++i2)
      #pragma unroll
      for (int j2 = 0; j2 < 2; ++j2)
        #pragma unroll
        for (int kk = 0; kk < 2; ++kk)
          acc[4 + i2][j2] = __builtin_amdgcn_mfma_f32_16x16x32_bf16(a[i2][kk], b[j2][kk], acc[4 + i2][j2], 0, 0, 0);
    __builtin_amdgcn_s_setprio(0);
    BARX();
  }

  // ---- epilogue ----
  #pragma unroll
  for (int i = 0; i < 8; ++i) {
    #pragma unroll
    for (int j = 0; j < 4; ++j) {
      const int n = n0 + wcn * 64 + j * 16 + l15;
      const int m_base = m0 + wr * 128 + i * 16 + (l4 << 2);
      const float bs = bias[n];
      #pragma unroll
      for (int r = 0; r < 4; ++r) {
        const int m = m_base + r;
        const float v = acc[i][j][r] + bs;
        const size_t off = (size_t)m * N + n;
        if constexpr (EPI == EPI_RES_F32) {
          ((float*)outp)[off] = res[off] + v;
        } else if constexpr (EPI == EPI_GELU_BF16) {
          float gv = 0.5f * v * (1.0f + erff(v * 0.70710678118654752f));
          ((short*)outp)[off] = f2bf(gv);
        } else {
          ((short*)outp)[off] = f2bf(v);
        }
      }
    }
  }
}

// ---------------- attention hop-bias precompute: battn[h][n][m] ----------------
__global__ __launch_bounds__(256) void attnbias_kernel(const float* __restrict__ H,
    const float* __restrict__ hop_logits, const float* __restrict__ rel_alpha,
    float* __restrict__ battn) {
  int t = threadIdx.x;
  for (int e = t; e < NHEADS * NTOK * NTOK; e += 256) {
    int h = e / (NTOK * NTOK);
    int nm = e - h * NTOK * NTOK;
    float l0 = hop_logits[h * 4 + 0], l1 = hop_logits[h * 4 + 1];
    float l2 = hop_logits[h * 4 + 2], l3 = hop_logits[h * 4 + 3];
    float mx = fmaxf(fmaxf(l0, l1), fmaxf(l2, l3));
    float e0 = expf(l0 - mx), e1 = expf(l1 - mx), e2 = expf(l2 - mx), e3 = expf(l3 - mx);
    float inv = 1.0f / (e0 + e1 + e2 + e3);
    float bsum = (e0 * H[0 * 289 + nm] + e1 * H[1 * 289 + nm] +
                  e2 * H[2 * 289 + nm] + e3 * H[3 * 289 + nm]) * inv;
    battn[e] = rel_alpha[h] * bsum;
  }
}

// ---------------- attention: one wave per (b,h) ----------------
__global__ __launch_bounds__(256) void attn_kernel(const short* __restrict__ qkv,
    const float* __restrict__ battn, short* __restrict__ out) {
  __shared__ __align__(16) short sq[4][NTOK * 64];
  __shared__ __align__(16) short sk[4][NTOK * 64];
  __shared__ __align__(16) short sv[4][NTOK * 64];
  __shared__ float sp[4][NTOK * 18];
  int w = threadIdx.x >> 6, lane = threadIdx.x & 63;
  int wid = blockIdx.x * 4 + w;
  int b = wid >> 3, h = wid & 7;

  for (int s = lane; s < NTOK * 8; s += 64) {
    int n = s >> 3, c8 = (s & 7) * 8;
    const short* rowp = qkv + (size_t)(b * NTOK + n) * 1536 + h * 64 + c8;
    *(s8v*)&sq[w][s * 8] = *(const s8v*)&rowp[0];
    *(s8v*)&sk[w][s * 8] = *(const s8v*)&rowp[512];
    *(s8v*)&sv[w][s * 8] = *(const s8v*)&rowp[1024];
  }
  __syncthreads();

  #pragma unroll
  for (int idx = 0; idx < 5; ++idx) {
    int e = idx * 64 + lane;
    int ec = e < 289 ? e : 288;
    int n = ec / 17, m = ec - n * 17;
    float acc = 0.f;
    #pragma unroll
    for (int c = 0; c < 8; ++c) {
      s8v qv = *(const s8v*)&sq[w][n * 64 + c * 8];
      s8v kv = *(const s8v*)&sk[w][m * 64 + c * 8];
      #pragma unroll
      for (int t = 0; t < 8; ++t) acc += bf2f(qv[t]) * bf2f(kv[t]);
    }
    if (e < 289) sp[w][n * 18 + m] = acc * 0.125f + battn[h * 289 + e];
  }
  __syncthreads();

  if (lane < NTOK) {
    float mx = -1e30f;
    #pragma unroll
    for (int m = 0; m < NTOK; ++m) mx = fmaxf(mx, sp[w][lane * 18 + m]);
    float pv[NTOK];
    float ssum = 0.f;
    #pragma unroll
    for (int m = 0; m < NTOK; ++m) { float ev = expf(sp[w][lane * 18 + m] - mx); pv[m] = ev; ssum += ev; }
    float inv = 1.0f / ssum;
    #pragma unroll
    for (int m = 0; m < NTOK; ++m) sp[w][lane * 18 + m] = pv[m] * inv;
  }
  __syncthreads();

  #pragma unroll
  for (int n = 0; n < NTOK; ++n) {
    float ov = 0.f;
    #pragma unroll
    for (int m = 0; m < NTOK; ++m) ov += sp[w][n * 18 + m] * bf2f(sv[w][m * 64 + lane]);
    out[(size_t)(b * NTOK + n) * DIMC + h * 64 + lane] = f2bf(ov);
  }
}

extern "C" void kernel_launch(void* const* d_in, const int* in_sizes, int n_in,
                              void* d_out, int out_size, void* d_ws, size_t ws_size,
                              hipStream_t stream) {
  const float* x_in       = (const float*)d_in[0];
  const float* Hstack     = (const float*)d_in[1];
  const float* hop_logits = (const float*)d_in[2];
  const float* rel_alpha  = (const float*)d_in[3];
  const float* qkv_w  = (const float*)d_in[4];
  const float* qkv_b  = (const float*)d_in[5];
  const float* proj_w = (const float*)d_in[6];
  const float* proj_b = (const float*)d_in[7];
  const float* ln1_g  = (const float*)d_in[8];
  const float* ln1_b  = (const float*)d_in[9];
  const float* ln2_g  = (const float*)d_in[10];
  const float* ln2_b  = (const float*)d_in[11];
  const float* fc1_w  = (const float*)d_in[12];
  const float* fc1_b  = (const float*)d_in[13];
  const float* fc2_w  = (const float*)d_in[14];
  const float* fc2_b  = (const float*)d_in[15];
  float* xout = (float*)d_out;

  // workspace layout
  short* wqkv  = (short*)d_ws;                       // 4*1536*512
  short* wproj = wqkv  + (size_t)4 * 1536 * 512;     // 4*512*512
  short* wfc1  = wproj + (size_t)4 * 512 * 512;      // 4*1024*512
  short* wfc2  = wfc1  + (size_t)4 * 1024 * 512;     // 4*512*1024
  float* battn = (float*)(wfc2 + (size_t)4 * 512 * 1024);  // 8*289 floats
  short* hbuf   = (short*)(battn + 2432);            // NROWS*512 bf16
  short* qkvbuf = hbuf + (size_t)NROWS * 512;        // NROWS*1536 bf16 (also fc1 hidden)

  {
    int n4;
    n4 = 4 * 1536 * 512 / 4;
    f2bf_kernel<<<dim3((n4 + 255) / 256), dim3(256), 0, stream>>>(qkv_w, wqkv, n4);
    n4 = 4 * 512 * 512 / 4;
    f2bf_kernel<<<dim3((n4 + 255) / 256), dim3(256), 0, stream>>>(proj_w, wproj, n4);
    n4 = 4 * 1024 * 512 / 4;
    f2bf_kernel<<<dim3((n4 + 255) / 256), dim3(256), 0, stream>>>(fc1_w, wfc1, n4);
    n4 = 4 * 512 * 1024 / 4;
    f2bf_kernel<<<dim3((n4 + 255) / 256), dim3(256), 0, stream>>>(fc2_w, wfc2, n4);
  }
  attnbias_kernel<<<dim3(1), dim3(256), 0, stream>>>(Hstack, hop_logits, rel_alpha, battn);

  const int LNBLK = NROWS / 4;      // 8704
  const dim3 B256(256), B512(512);
  const int MB = NROWS / 256;       // 136

  for (int d = 0; d < DEPTHL; ++d) {
    const float* xres = (d == 0) ? x_in : xout;
    // LN1 -> h (bf16)
    ln_kernel<<<dim3(LNBLK), B256, 0, stream>>>(xres, ln1_g + d * 512, ln1_b + d * 512, hbuf);
    // QKV GEMM -> qkvbuf bf16
    gemm8p<512, EPI_BF16><<<dim3((1536 / 256) * MB), B512, 0, stream>>>(
        hbuf, wqkv + (size_t)d * 1536 * 512, qkv_b + d * 1536, nullptr, qkvbuf, 1536, 1536 / 256);
    // attention -> hbuf
    attn_kernel<<<dim3(2048 * NHEADS / 4), B256, 0, stream>>>(qkvbuf, battn, hbuf);
    // proj GEMM + residual -> xout (fp32)
    gemm8p<512, EPI_RES_F32><<<dim3((512 / 256) * MB), B512, 0, stream>>>(
        hbuf, wproj + (size_t)d * 512 * 512, proj_b + d * 512, xres, xout, 512, 512 / 256);
    // LN2 -> h (bf16)
    ln_kernel<<<dim3(LNBLK), B256, 0, stream>>>(xout, ln2_g + d * 512, ln2_b + d * 512, hbuf);
    // fc1 GEMM + GELU -> qkvbuf (bf16 hidden)
    gemm8p<512, EPI_GELU_BF16><<<dim3((1024 / 256) * MB), B512, 0, stream>>>(
        hbuf, wfc1 + (size_t)d * 1024 * 512, fc1_b + d * 1024, nullptr, qkvbuf, 1024, 1024 / 256);
    // fc2 GEMM + residual -> xout (fp32)
    gemm8p<1024, EPI_RES_F32><<<dim3((512 / 256) * MB), B512, 0, stream>>>(
        qkvbuf, wfc2 + (size_t)d * 512 * 1024, fc2_b + d * 512, xout, xout, 512, 512 / 256);
  }
}

// Round 3
// 1831.388 us; speedup vs baseline: 1.1889x; 1.1889x over previous
//
#include <hip/hip_runtime.h>

#define DEPTHL 4
#define NHEADS 8
#define DIMC 512
#define HIDDENC 1024
#define NTOK 17
#define NROWS (2048*NTOK)   // 34816

typedef __attribute__((ext_vector_type(8))) short s8v;
typedef __attribute__((ext_vector_type(4))) float f4v;
typedef __attribute__((ext_vector_type(4))) short s4v;

static __device__ __forceinline__ float bf2f(short s) {
  unsigned u = ((unsigned)(unsigned short)s) << 16;
  return __builtin_bit_cast(float, u);
}
static __device__ __forceinline__ short f2bf(float f) {
  unsigned u = __builtin_bit_cast(unsigned, f);
  u += 0x7fffu + ((u >> 16) & 1u);
  return (short)(u >> 16);
}

static __device__ __forceinline__ void load_lds16(const void* g, void* l) {
  __builtin_amdgcn_global_load_lds(
      (const __attribute__((address_space(1))) unsigned int*)g,
      (__attribute__((address_space(3))) unsigned int*)l, 16, 0, 0);
}

#define BARX() asm volatile("s_barrier" ::: "memory")
#define VMC0() asm volatile("s_waitcnt vmcnt(0)" ::: "memory")

// ---------------- weight fp32 -> bf16 convert ----------------
__global__ __launch_bounds__(256) void f2bf_kernel(const float* __restrict__ in,
                                                   short* __restrict__ out, int n4) {
  int i = blockIdx.x * 256 + threadIdx.x;
  if (i < n4) {
    float4 v = ((const float4*)in)[i];
    s4v o;
    o[0] = f2bf(v.x); o[1] = f2bf(v.y); o[2] = f2bf(v.z); o[3] = f2bf(v.w);
    ((s4v*)out)[i] = o;
  }
}

// ---------------- LayerNorm -> bf16 ----------------
__global__ __launch_bounds__(256) void ln_kernel(const float* __restrict__ x,
    const float* __restrict__ g, const float* __restrict__ b,
    short* __restrict__ h) {
  int row = blockIdx.x * 4 + (threadIdx.x >> 6);
  int lane = threadIdx.x & 63;
  const float* xr = x + (size_t)row * DIMC + lane * 8;
  float4 v0 = *(const float4*)xr;
  float4 v1 = *(const float4*)(xr + 4);
  float s = v0.x + v0.y + v0.z + v0.w + v1.x + v1.y + v1.z + v1.w;
  #pragma unroll
  for (int o = 32; o > 0; o >>= 1) s += __shfl_xor(s, o, 64);
  float mean = s * (1.0f / 512.0f);
  float d0 = v0.x-mean, d1 = v0.y-mean, d2 = v0.z-mean, d3 = v0.w-mean;
  float d4 = v1.x-mean, d5 = v1.y-mean, d6 = v1.z-mean, d7 = v1.w-mean;
  float vs = d0*d0+d1*d1+d2*d2+d3*d3+d4*d4+d5*d5+d6*d6+d7*d7;
  #pragma unroll
  for (int o = 32; o > 0; o >>= 1) vs += __shfl_xor(vs, o, 64);
  float rstd = rsqrtf(vs * (1.0f / 512.0f) + 1e-5f);
  const float* gp = g + lane * 8;
  const float* bp = b + lane * 8;
  float4 g0 = *(const float4*)gp, g1 = *(const float4*)(gp + 4);
  float4 b0 = *(const float4*)bp, b1 = *(const float4*)(bp + 4);
  s8v o;
  o[0] = f2bf(d0 * rstd * g0.x + b0.x);
  o[1] = f2bf(d1 * rstd * g0.y + b0.y);
  o[2] = f2bf(d2 * rstd * g0.z + b0.z);
  o[3] = f2bf(d3 * rstd * g0.w + b0.w);
  o[4] = f2bf(d4 * rstd * g1.x + b1.x);
  o[5] = f2bf(d5 * rstd * g1.y + b1.y);
  o[6] = f2bf(d6 * rstd * g1.z + b1.z);
  o[7] = f2bf(d7 * rstd * g1.w + b1.w);
  *(s8v*)(h + (size_t)row * DIMC + lane * 8) = o;
}

// ---------------- 2-phase double-buffered 128^2 GEMM ----------------
// out[m,n] = sum_k A[m,k]*W[n,k] (+bias, epilogue). LDS XOR-swizzled
// (inverse-swizzled global source + swizzled ds_read; verified conflict-free).
enum { EPI_BF16 = 0, EPI_RES_F32 = 1, EPI_GELU_BF16 = 2 };

template<int K, int EPI>
__global__ __launch_bounds__(256) void gemm2p(
    const short* __restrict__ A, const short* __restrict__ Bm,
    const float* __restrict__ bias, const float* __restrict__ res,
    void* __restrict__ outp, int N, int nbx) {
  constexpr int NT = K / 64;
  __shared__ __align__(16) short SA[2][8192];   // [buf][128 rows][64]
  __shared__ __align__(16) short SB[2][8192];
  const int tid = threadIdx.x;
  const int wave = tid >> 6, lane = tid & 63;
  const int l15 = lane & 15, l4 = lane >> 4;
  // T1: XCD-aware bijective swizzle (nwg % 8 == 0 for all our grids)
  const int nwg = gridDim.x, bid = blockIdx.x;
  const int swz = (bid & 7) * (nwg >> 3) + (bid >> 3);
  const int bx = swz % nbx, by = swz / nbx;
  const int m0 = by * 128, n0 = bx * 128;
  const int wr = wave >> 1, wc = wave & 1;

  f4v acc[4][4] = {};

  // stage a 128x64 tile (8 loads/thread over 4 calls of 32 rows):
  // linear LDS dest (global_load_lds requirement), inverse-swizzled source.
  auto stageT = [&](const short* __restrict__ mat, int row0, int k0, short* ldsb) {
    #pragma unroll
    for (int q = 0; q < 4; ++q) {
      const int r = q * 32 + (tid >> 3), c = tid & 7;
      const short* src = mat + (size_t)(row0 + r) * K + k0 + ((c ^ (r & 7)) << 3);
      load_lds16(src, ldsb + q * 2048 + ((tid & ~63) << 3));
    }
  };

  stageT(A, m0, 0, SA[0]);
  stageT(Bm, n0, 0, SB[0]);
  VMC0();
  BARX();

  #pragma unroll
  for (int t = 0; t < NT; ++t) {
    const int cur = t & 1;
    if (t + 1 < NT) {                 // T3-minimum: issue next-tile stages FIRST
      stageT(A, m0, (t + 1) * 64, SA[cur ^ 1]);
      stageT(Bm, n0, (t + 1) * 64, SB[cur ^ 1]);
    }
    #pragma unroll
    for (int kk = 0; kk < 2; ++kk) {
      s8v af[4], bfr[4];
      #pragma unroll
      for (int i = 0; i < 4; ++i) {
        const int Ra = wr * 64 + i * 16 + l15;
        af[i] = *(const s8v*)&SA[cur][(Ra << 6) + (((kk * 4 + l4) ^ (Ra & 7)) << 3)];
        const int Rb = wc * 64 + i * 16 + l15;
        bfr[i] = *(const s8v*)&SB[cur][(Rb << 6) + (((kk * 4 + l4) ^ (Rb & 7)) << 3)];
      }
      #pragma unroll
      for (int i = 0; i < 4; ++i)
        #pragma unroll
        for (int j = 0; j < 4; ++j)
          acc[i][j] = __builtin_amdgcn_mfma_f32_16x16x32_bf16(af[i], bfr[j], acc[i][j], 0, 0, 0);
    }
    if (t + 1 < NT) VMC0();           // next buffer landed (hidden under compute)
    BARX();                           // all waves done reading cur before overwrite
  }

  // ---- epilogue: C/D layout col=lane&15, row=(lane>>4)*4+r ----
  const int cb = n0 + wc * 64 + l15;
  const int rb = m0 + wr * 64 + (l4 << 2);
  #pragma unroll
  for (int i = 0; i < 4; ++i) {
    #pragma unroll
    for (int j2 = 0; j2 < 4; ++j2) {
      const int n = cb + j2 * 16;
      const float bs = bias[n];
      #pragma unroll
      for (int r = 0; r < 4; ++r) {
        const int m = rb + i * 16 + r;
        const float v = acc[i][j2][r] + bs;
        const size_t off = (size_t)m * N + n;
        if constexpr (EPI == EPI_RES_F32) {
          ((float*)outp)[off] = res[off] + v;
        } else if constexpr (EPI == EPI_GELU_BF16) {
          float gv = 0.5f * v * (1.0f + erff(v * 0.70710678118654752f));
          ((short*)outp)[off] = f2bf(gv);
        } else {
          ((short*)outp)[off] = f2bf(v);
        }
      }
    }
  }
}

// ---------------- attention hop-bias precompute: battn[h][n][m] ----------------
__global__ __launch_bounds__(256) void attnbias_kernel(const float* __restrict__ H,
    const float* __restrict__ hop_logits, const float* __restrict__ rel_alpha,
    float* __restrict__ battn) {
  int t = threadIdx.x;
  for (int e = t; e < NHEADS * NTOK * NTOK; e += 256) {
    int h = e / (NTOK * NTOK);
    int nm = e - h * NTOK * NTOK;
    float l0 = hop_logits[h * 4 + 0], l1 = hop_logits[h * 4 + 1];
    float l2 = hop_logits[h * 4 + 2], l3 = hop_logits[h * 4 + 3];
    float mx = fmaxf(fmaxf(l0, l1), fmaxf(l2, l3));
    float e0 = expf(l0 - mx), e1 = expf(l1 - mx), e2 = expf(l2 - mx), e3 = expf(l3 - mx);
    float inv = 1.0f / (e0 + e1 + e2 + e3);
    float bsum = (e0 * H[0 * 289 + nm] + e1 * H[1 * 289 + nm] +
                  e2 * H[2 * 289 + nm] + e3 * H[3 * 289 + nm]) * inv;
    battn[e] = rel_alpha[h] * bsum;
  }
}

// ---------------- attention: one wave per (b,h) ----------------
__global__ __launch_bounds__(256) void attn_kernel(const short* __restrict__ qkv,
    const float* __restrict__ battn, short* __restrict__ out) {
  __shared__ __align__(16) short sq[4][NTOK * 64];
  __shared__ __align__(16) short sk[4][NTOK * 64];
  __shared__ __align__(16) short sv[4][NTOK * 64];
  __shared__ float sp[4][NTOK * 18];
  int w = threadIdx.x >> 6, lane = threadIdx.x & 63;
  int wid = blockIdx.x * 4 + w;
  int b = wid >> 3, h = wid & 7;

  for (int s = lane; s < NTOK * 8; s += 64) {
    int n = s >> 3, c8 = (s & 7) * 8;
    const short* rowp = qkv + (size_t)(b * NTOK + n) * 1536 + h * 64 + c8;
    *(s8v*)&sq[w][s * 8] = *(const s8v*)&rowp[0];
    *(s8v*)&sk[w][s * 8] = *(const s8v*)&rowp[512];
    *(s8v*)&sv[w][s * 8] = *(const s8v*)&rowp[1024];
  }
  __syncthreads();

  #pragma unroll
  for (int idx = 0; idx < 5; ++idx) {
    int e = idx * 64 + lane;
    int ec = e < 289 ? e : 288;
    int n = ec / 17, m = ec - n * 17;
    float acc = 0.f;
    #pragma unroll
    for (int c = 0; c < 8; ++c) {
      s8v qv = *(const s8v*)&sq[w][n * 64 + c * 8];
      s8v kv = *(const s8v*)&sk[w][m * 64 + c * 8];
      #pragma unroll
      for (int t = 0; t < 8; ++t) acc += bf2f(qv[t]) * bf2f(kv[t]);
    }
    if (e < 289) sp[w][n * 18 + m] = acc * 0.125f + battn[h * 289 + e];
  }
  __syncthreads();

  if (lane < NTOK) {
    float mx = -1e30f;
    #pragma unroll
    for (int m = 0; m < NTOK; ++m) mx = fmaxf(mx, sp[w][lane * 18 + m]);
    float pv[NTOK];
    float ssum = 0.f;
    #pragma unroll
    for (int m = 0; m < NTOK; ++m) { float ev = expf(sp[w][lane * 18 + m] - mx); pv[m] = ev; ssum += ev; }
    float inv = 1.0f / ssum;
    #pragma unroll
    for (int m = 0; m < NTOK; ++m) sp[w][lane * 18 + m] = pv[m] * inv;
  }
  __syncthreads();

  #pragma unroll
  for (int n = 0; n < NTOK; ++n) {
    float ov = 0.f;
    #pragma unroll
    for (int m = 0; m < NTOK; ++m) ov += sp[w][n * 18 + m] * bf2f(sv[w][m * 64 + lane]);
    out[(size_t)(b * NTOK + n) * DIMC + h * 64 + lane] = f2bf(ov);
  }
}

extern "C" void kernel_launch(void* const* d_in, const int* in_sizes, int n_in,
                              void* d_out, int out_size, void* d_ws, size_t ws_size,
                              hipStream_t stream) {
  const float* x_in       = (const float*)d_in[0];
  const float* Hstack     = (const float*)d_in[1];
  const float* hop_logits = (const float*)d_in[2];
  const float* rel_alpha  = (const float*)d_in[3];
  const float* qkv_w  = (const float*)d_in[4];
  const float* qkv_b  = (const float*)d_in[5];
  const float* proj_w = (const float*)d_in[6];
  const float* proj_b = (const float*)d_in[7];
  const float* ln1_g  = (const float*)d_in[8];
  const float* ln1_b  = (const float*)d_in[9];
  const float* ln2_g  = (const float*)d_in[10];
  const float* ln2_b  = (const float*)d_in[11];
  const float* fc1_w  = (const float*)d_in[12];
  const float* fc1_b  = (const float*)d_in[13];
  const float* fc2_w  = (const float*)d_in[14];
  const float* fc2_b  = (const float*)d_in[15];
  float* xout = (float*)d_out;

  // workspace layout
  short* wqkv  = (short*)d_ws;                       // 4*1536*512
  short* wproj = wqkv  + (size_t)4 * 1536 * 512;     // 4*512*512
  short* wfc1  = wproj + (size_t)4 * 512 * 512;      // 4*1024*512
  short* wfc2  = wfc1  + (size_t)4 * 1024 * 512;     // 4*512*1024
  float* battn = (float*)(wfc2 + (size_t)4 * 512 * 1024);  // 8*289 floats
  short* hbuf   = (short*)(battn + 2432);            // NROWS*512 bf16
  short* qkvbuf = hbuf + (size_t)NROWS * 512;        // NROWS*1536 bf16 (also fc1 hidden)

  {
    int n4;
    n4 = 4 * 1536 * 512 / 4;
    f2bf_kernel<<<dim3((n4 + 255) / 256), dim3(256), 0, stream>>>(qkv_w, wqkv, n4);
    n4 = 4 * 512 * 512 / 4;
    f2bf_kernel<<<dim3((n4 + 255) / 256), dim3(256), 0, stream>>>(proj_w, wproj, n4);
    n4 = 4 * 1024 * 512 / 4;
    f2bf_kernel<<<dim3((n4 + 255) / 256), dim3(256), 0, stream>>>(fc1_w, wfc1, n4);
    n4 = 4 * 512 * 1024 / 4;
    f2bf_kernel<<<dim3((n4 + 255) / 256), dim3(256), 0, stream>>>(fc2_w, wfc2, n4);
  }
  attnbias_kernel<<<dim3(1), dim3(256), 0, stream>>>(Hstack, hop_logits, rel_alpha, battn);

  const int LNBLK = NROWS / 4;      // 8704
  const dim3 B256(256);
  const int MB = NROWS / 128;       // 272

  for (int d = 0; d < DEPTHL; ++d) {
    const float* xres = (d == 0) ? x_in : xout;
    // LN1 -> h (bf16)
    ln_kernel<<<dim3(LNBLK), B256, 0, stream>>>(xres, ln1_g + d * 512, ln1_b + d * 512, hbuf);
    // QKV GEMM -> qkvbuf bf16
    gemm2p<512, EPI_BF16><<<dim3((1536 / 128) * MB), B256, 0, stream>>>(
        hbuf, wqkv + (size_t)d * 1536 * 512, qkv_b + d * 1536, nullptr, qkvbuf, 1536, 1536 / 128);
    // attention -> hbuf
    attn_kernel<<<dim3(2048 * NHEADS / 4), B256, 0, stream>>>(qkvbuf, battn, hbuf);
    // proj GEMM + residual -> xout (fp32)
    gemm2p<512, EPI_RES_F32><<<dim3((512 / 128) * MB), B256, 0, stream>>>(
        hbuf, wproj + (size_t)d * 512 * 512, proj_b + d * 512, xres, xout, 512, 512 / 128);
    // LN2 -> h (bf16)
    ln_kernel<<<dim3(LNBLK), B256, 0, stream>>>(xout, ln2_g + d * 512, ln2_b + d * 512, hbuf);
    // fc1 GEMM + GELU -> qkvbuf (bf16 hidden)
    gemm2p<512, EPI_GELU_BF16><<<dim3((1024 / 128) * MB), B256, 0, stream>>>(
        hbuf, wfc1 + (size_t)d * 1024 * 512, fc1_b + d * 1024, nullptr, qkvbuf, 1024, 1024 / 128);
    // fc2 GEMM + residual -> xout (fp32)
    gemm2p<1024, EPI_RES_F32><<<dim3((512 / 128) * MB), B256, 0, stream>>>(
        qkvbuf, wfc2 + (size_t)d * 512 * 1024, fc2_b + d * 512, xout, xout, 512, 512 / 128);
  }
}